// Round 11
// baseline (331.027 us; speedup 1.0000x reference)
//
#include <hip/hip_runtime.h>

// Problem constants
#define B_  4
#define T_  2048
#define C_  1024
#define NH_ 16
#define HD_ 64
#define BT_ (B_*T_)   // 8192
#define N3C (3*C_)    // 3072

typedef _Float16 f16;
typedef _Float16 half8 __attribute__((ext_vector_type(8)));
typedef _Float16 half4 __attribute__((ext_vector_type(4)));
typedef _Float16 half2v __attribute__((ext_vector_type(2)));
typedef float f32x4 __attribute__((ext_vector_type(4)));

// Async global->LDS, 16 B per lane.
__device__ __forceinline__ void gld16(const f16* g, f16* l) {
  __builtin_amdgcn_global_load_lds(
      (const __attribute__((address_space(1))) unsigned int*)g,
      (__attribute__((address_space(3))) unsigned int*)l, 16, 0, 0);
}

// Single-instruction exp2 (v_exp_f32). Inputs here are bounded (scores) or
// -1e9 (mask), where HW gives 0 — no libm denormal fixup needed.
__device__ __forceinline__ float fast_exp2(float x) {
#if __has_builtin(__builtin_amdgcn_exp2f)
  return __builtin_amdgcn_exp2f(x);
#else
  return exp2f(x);
#endif
}

// Packed f32x2 -> f16x2 convert (v_cvt_pkrtz_f16_f32); bit-cast fixes the
// __fp16-vs-_Float16 ext-vector type mismatch (same bits). RTZ — used only
// for softmax p-values, NOT for input conversion.
__device__ __forceinline__ half2v cvt_pk_f16(float a, float b) {
#if __has_builtin(__builtin_amdgcn_cvt_pkrtz)
  return __builtin_bit_cast(half2v, __builtin_amdgcn_cvt_pkrtz(a, b));
#else
  half2v r; r[0] = (f16)a; r[1] = (f16)b; return r;
#endif
}

// ---------------------------------------------------------------------------
// Merged pre-pass (R8 form — the f16 x16 intermediate pays for itself via
// 24x column-block reuse in gemm_qkv; R10's fp32-A fusion doubled FETCH):
// [0,4096) cvt_x | [4096,4864) W_attn^T | [4864,5120) W_proj^T
// | [5120,5376) RoPE table.
// ---------------------------------------------------------------------------
__global__ __launch_bounds__(256) void prep(
    const float* __restrict__ X, f16* __restrict__ X16,
    const float* __restrict__ Wa, f16* __restrict__ Wta,
    const float* __restrict__ Wp, f16* __restrict__ Wtp,
    float2* __restrict__ cs)
{
  __shared__ float Ls[64][65];
  const int tid = threadIdx.x;
  const int blk = blockIdx.x;
  if (blk < 4096) {               // x fp32 -> f16
    const int i = blk * 256 + tid;
    const float4 a = ((const float4*)X)[i * 2];
    const float4 b = ((const float4*)X)[i * 2 + 1];
    half8 hx;
    hx[0] = (f16)a.x; hx[1] = (f16)a.y; hx[2] = (f16)a.z; hx[3] = (f16)a.w;
    hx[4] = (f16)b.x; hx[5] = (f16)b.y; hx[6] = (f16)b.z; hx[7] = (f16)b.w;
    ((half8*)X16)[i] = hx;
    return;
  }
  if (blk >= 5120) {              // RoPE cos/sin table
    const int i = (blk - 5120) * 256 + tid;
    const int f = i & 31, t = i >> 5;
    const float inv = expf(-(2.0f * (float)f / 64.0f) * 9.210340371976184f);
    float sn, cn;
    sincosf((float)t * inv, &sn, &cn);
    cs[i] = make_float2(cn, sn);
    return;
  }
  // Transpose + cvt: W (K x N fp32) -> Wt (N x K f16), 64x64 tiles.
  const float* W; f16* Wt; int N, i2;
  if (blk < 4864) { W = Wa; Wt = Wta; N = N3C; i2 = blk - 4096; }
  else            { W = Wp; Wt = Wtp; N = C_;  i2 = blk - 4864; }
  const int nblk = N >> 6;
  const int n0 = (i2 % nblk) * 64, k0 = (i2 / nblk) * 64;
#pragma unroll
  for (int j = 0; j < 4; ++j) {
    const int idx = j * 256 + tid;
    const int r = idx >> 4, c = (idx & 15) * 4;
    const float4 w = *(const float4*)(W + (size_t)(k0 + r) * N + n0 + c);
    Ls[r][c + 0] = w.x; Ls[r][c + 1] = w.y; Ls[r][c + 2] = w.z; Ls[r][c + 3] = w.w;
  }
  __syncthreads();
#pragma unroll
  for (int j = 0; j < 2; ++j) {
    const int idx = j * 256 + tid;
    const int r = idx >> 3, c = (idx & 7) * 8;
    half8 hw;
#pragma unroll
    for (int u = 0; u < 8; ++u) hw[u] = (f16)Ls[c + u][r];
    *(half8*)(Wt + (size_t)(n0 + r) * C_ + k0 + c) = hw;
  }
}

// ---------------------------------------------------------------------------
// Kernel 1: qkv GEMM + fused RoPE (table). BK=64, XOR-swizzled LDS,
// global_load_lds(16B) on f16 A and B (verified R8/R9, ~78 us).
// Q/K epilogue: LDS bounce -> coalesced half8 stores (verified R9).
// V epilogue: LDS transpose -> coalesced half8 stores along t (verified R5).
// ---------------------------------------------------------------------------
__global__ __launch_bounds__(256) void gemm_qkv(
    const f16* __restrict__ A, const f16* __restrict__ Bt,
    const float* __restrict__ bias, const float2* __restrict__ cs,
    f16* __restrict__ Qo, f16* __restrict__ Ko, f16* __restrict__ Vt_g)
{
  __shared__ f16 S[16384];         // As = S[0:8192), Bs = S[8192:16384)
  f16* As = S;
  f16* Bs = S + 8192;
  const int tid  = threadIdx.x;
  const int row0 = blockIdx.y * 128;
  const int col0 = blockIdx.x * 128;
  const int wave = tid >> 6, lane = tid & 63;
  const int l = lane & 15, quad = lane >> 4;
  const int wm = wave >> 1, wn = wave & 1;
  const int sr = tid >> 3;
  const int scs = ((tid & 7) ^ (sr & 7)) * 8;
  const int lq7 = l & 7;

  f32x4 acc[4][4];
#pragma unroll
  for (int mi = 0; mi < 4; ++mi)
#pragma unroll
    for (int ni = 0; ni < 4; ++ni) acc[mi][ni] = (f32x4)0.0f;

  for (int k0 = 0; k0 < C_; k0 += 64) {
    __syncthreads();
#pragma unroll
    for (int p = 0; p < 4; ++p) {
      const int r = p * 32 + sr;
      gld16(A  + (size_t)(row0 + r) * C_ + k0 + scs, &As[p * 2048 + tid * 8]);
      gld16(Bt + (size_t)(col0 + r) * C_ + k0 + scs, &Bs[p * 2048 + tid * 8]);
    }
    __syncthreads();

#pragma unroll
    for (int s = 0; s < 2; ++s) {
      half8 af[4], bf[4];
#pragma unroll
      for (int mi = 0; mi < 4; ++mi)
        af[mi] = *(const half8*)&As[(wm * 64 + mi * 16 + l) * 64 + ((((s << 2) | quad) ^ lq7) << 3)];
#pragma unroll
      for (int ni = 0; ni < 4; ++ni)
        bf[ni] = *(const half8*)&Bs[(wn * 64 + ni * 16 + l) * 64 + ((((s << 2) | quad) ^ lq7) << 3)];
#pragma unroll
      for (int mi = 0; mi < 4; ++mi)
#pragma unroll
        for (int ni = 0; ni < 4; ++ni)
          acc[mi][ni] = __builtin_amdgcn_mfma_f32_16x16x32_f16(af[mi], bf[ni], acc[mi][ni], 0, 0, 0);
    }
  }

  const int region = col0 >> 10;           // 0=q 1=k 2=v
  const int colw = col0 + wn * 64;
  const int bloc  = row0 >> 11;
  const int tbase = row0 & (T_ - 1);
  if (region < 2) {
    f16* dst = (region == 0) ? Qo : Ko;
    const float qs = (region == 0) ? 0.18033688f : 1.0f;   // 0.125*log2(e)
    // Phase 1: RoPE + bias into LDS tile S[wn][t][d], swizzled.
    __syncthreads();                        // staging-buffer reads done
#pragma unroll
    for (int mi = 0; mi < 4; ++mi) {
#pragma unroll
      for (int r = 0; r < 4; ++r) {
        const int t = wm * 64 + mi * 16 + quad * 4 + r;   // 0..127
        const int swz = ((t >> 2) & 3) << 3;
        const float2* csrow = cs + (tbase + t) * 32;
#pragma unroll
        for (int ni = 0; ni < 2; ++ni) {
          const int d = ni * 16 + l;
          const float2 c2 = csrow[d];
          const float x1 = acc[mi][ni][r]     + bias[colw + d];
          const float x2 = acc[mi][ni + 2][r] + bias[colw + d + 32];
          S[wn * 8192 + t * 64 + (d ^ swz)]        = (f16)((x1 * c2.x - x2 * c2.y) * qs);
          S[wn * 8192 + t * 64 + ((d + 32) ^ swz)] = (f16)((x2 * c2.x + x1 * c2.y) * qs);
        }
      }
    }
    __syncthreads();
    // Phase 2: coalesced half8 stores along d (8 rows x 128 B per wave instr).
#pragma unroll
    for (int j = 0; j < 8; ++j) {
      const int flat = j * 256 + tid;
      const int wnn  = flat >> 10;                      // 0..1
      const int rem  = flat & 1023;
      const int t    = rem >> 3;                        // 0..127
      const int d8   = rem & 7;                         // 0..7
      const int swz  = (t >> 2) & 3;
      const half8 v  = *(const half8*)&S[wnn * 8192 + t * 64 + ((d8 ^ swz) << 3)];
      const int hh   = ((col0 + wnn * 64) & 1023) >> 6;
      *(half8*)(dst + ((size_t)(bloc * NH_ + hh) * T_ + tbase + t) * HD_ + d8 * 8) = v;
    }
  } else {
    // V: transpose via LDS, then coalesced half8 stores along t.
    __syncthreads();                        // all staging-buffer reads done
#pragma unroll
    for (int mi = 0; mi < 4; ++mi) {
      const int t_loc = wm * 64 + mi * 16 + quad * 4;   // 4-aligned
#pragma unroll
      for (int ni = 0; ni < 4; ++ni) {
        const int d = ni * 16 + l;
        const float bs = bias[colw + d];
        half4 o;
#pragma unroll
        for (int r = 0; r < 4; ++r) o[r] = (f16)(acc[mi][ni][r] + bs);
        const int ts = t_loc ^ ((d & 15) << 3);         // swizzle keeps 4-blocks intact
        *(half4*)&S[wn * 8192 + d * 128 + ts] = o;
      }
    }
    __syncthreads();
#pragma unroll
    for (int j = 0; j < 8; ++j) {
      const int flat = j * 256 + tid;
      const int buf  = flat >> 10;                      // 0..1 (= wn half)
      const int rem  = flat & 1023;
      const int d    = rem >> 4;                        // 0..63
      const int tt   = (rem & 15) << 3;                 // 0,8,..,120
      const half8 v  = *(const half8*)&S[buf * 8192 + d * 128 + (tt ^ ((d & 15) << 3))];
      const int hh   = ((col0 + buf * 64) & 1023) >> 6;
      *(half8*)(Vt_g + ((size_t)((bloc * NH_ + hh) * HD_ + d)) * T_ + tbase + tt) = v;
    }
  }
}

// ---------------------------------------------------------------------------
// Kernel 3: MFMA flash attention — 8-WAVE SHARED-STAGING balanced pairs.
// Block = 512 threads = 8 waves, owning pair (qta=31-pr, qtb=pr).
// Waves 0-3 compute q-tile qta (16 rows each), waves 4-7 q-tile qtb, BOTH
// consuming one shared K/V staging per key-tile in a single fused k-loop
// (kt = 0..qta). Light-tile waves compute only while kt <= qtb (wave-uniform
// guard OUTSIDE the MFMA loops — not R4's per-lane branch).
// vs R8: waves/CU 16 -> 32 (4 blocks x 8 waves; VGPR<=64 via launch_bounds,
// LDS 4x32KB=128<=160), stagings per pair 33 -> qta+1, K/V HBM refetch
// halved. Per-wave compute code identical to verified R5/R8 body.
// Ping-pong safety: passing barrier kt implies all waves finished
// compute_{kt-1} (reads of buffer (kt+1)&1), so writes cannot race.
// Fixed-shift softmax, scale pre-folded into Q: p = exp2(S).
// XCD-bijective swizzle (nwg=1024): all 16 pairs of a bh on one XCD's L2.
// ---------------------------------------------------------------------------
__global__ __launch_bounds__(512, 8) void attn_mfma(
    const f16* __restrict__ Qg, const f16* __restrict__ Kg,
    const f16* __restrict__ Vt_g, f16* __restrict__ Y)
{
  __shared__ f16 Ks[2][64 * 64];   // [buf][key][hd], swizzled
  __shared__ f16 Vt[2][64 * 64];   // [buf][hd][key], swizzled
  const int tid  = threadIdx.x;
  // XCD-bijective swizzle (nwg = 1024, divisible by 8).
  const int w    = (blockIdx.x & 7) * 128 + (blockIdx.x >> 3);
  const int bh   = w >> 4;                   // 0..63
  const int pr   = w & 15;                   // pair index 0..15
  const int qta  = 31 - pr;                  // heavy q-tile (waves 0-3)
  const int qtb  = pr;                       // light q-tile (waves 4-7)
  const int b    = bh >> 4, h = bh & 15;
  const int wave = tid >> 6, lane = tid & 63;
  const int l    = lane & 15, quad = lane >> 4;
  const int lq7  = l & 7;
  const int r0   = tid >> 3, cc = tid & 7;   // r0 in [0,64): one row per thread
  const int u    = wave >> 2, wq = wave & 3; // u: which q-tile; wq: 16-row slice
  const int qt   = u ? qtb : qta;
  const int qrow = qt * 64 + wq * 16 + l;

  const f16* kbase  = Kg   + (size_t)bh * T_ * HD_;
  const f16* vtbase = Vt_g + (size_t)bh * HD_ * T_;

  // Q fragments: 16 q-rows per wave, d = 0..63 in two K=32 chunks.
  half8 qf[2];
  {
    const f16* qp = Qg + ((size_t)bh * T_ + qrow) * HD_;
    qf[0] = *(const half8*)(qp + quad * 8);
    qf[1] = *(const half8*)(qp + 32 + quad * 8);
  }

  f32x4 O[4];
#pragma unroll
  for (int mi = 0; mi < 4; ++mi) O[mi] = (f32x4)0.0f;
  float l_run = 0.f;
  const f32x4 zz = (f32x4)0.0f;              // shared MFMA C-zero

  // Prefetch tile 0 into registers (one K half8 + one V half8 per thread).
  half8 hk = *(const half8*)(kbase + (size_t)r0 * HD_ + cc * 8);
  half8 hv = *(const half8*)(vtbase + (size_t)r0 * T_ + cc * 8);

  const int nkt = qta + 1;
  const int cst = ((cc ^ (r0 & 7)) << 3);

  for (int kt = 0; kt < nkt; ++kt) {
    f16* KsB = Ks[kt & 1];
    f16* VtB = Vt[kt & 1];
    // Write prefetched tile to this iteration's LDS buffer (all 512 threads).
    *(half8*)&KsB[r0 * 64 + cst] = hk;
    *(half8*)&VtB[r0 * 64 + cst] = hv;
    __syncthreads();
    // Issue next tile's global loads; latency overlaps the compute below.
    if (kt + 1 < nkt) {
      hk = *(const half8*)(kbase + (size_t)((kt + 1) * 64 + r0) * HD_ + cc * 8);
      hv = *(const half8*)(vtbase + (size_t)r0 * T_ + (kt + 1) * 64 + cc * 8);
    }

    if (u == 0 || kt <= qtb) {               // wave-uniform
      // S^T = K · Q^T (16 q-cols per wave); first MFMA uses shared zero C.
      f32x4 St[4];
#pragma unroll
      for (int st = 0; st < 4; ++st) {
        const int row = st * 16 + l;
        const half8 af0 = *(const half8*)&KsB[row * 64 + (((quad) ^ lq7) << 3)];
        St[st] = __builtin_amdgcn_mfma_f32_16x16x32_f16(af0, qf[0], zz, 0, 0, 0);
        const half8 af1 = *(const half8*)&KsB[row * 64 + (((4 | quad) ^ lq7) << 3)];
        St[st] = __builtin_amdgcn_mfma_f32_16x16x32_f16(af1, qf[1], St[st], 0, 0, 0);
      }

      // p = exp2(S) (scale folded into Q; shift constant cancels in O/l).
      const bool domask = (kt == qt);
      const int k0 = kt * 64;
      half4 pf[4];
      float psum = 0.f;
#pragma unroll
      for (int st = 0; st < 4; ++st) {
        float pv[4];
#pragma unroll
        for (int r = 0; r < 4; ++r) {
          float x = St[st][r];
          if (domask) {
            const int key = k0 + st * 16 + quad * 4 + r;
            if (key > qrow) x = -1e9f;
          }
          const float ev = fast_exp2(x);
          pv[r] = ev;
          psum += ev;
        }
        const half2v lo = cvt_pk_f16(pv[0], pv[1]);
        const half2v hi = cvt_pk_f16(pv[2], pv[3]);
        pf[st][0] = lo[0]; pf[st][1] = lo[1];
        pf[st][2] = hi[0]; pf[st][3] = hi[1];
      }
      l_run += psum;

      // O^T += V^T · P^T.
#pragma unroll
      for (int mi = 0; mi < 4; ++mi) {
        const int row = mi * 16 + l;
#pragma unroll
        for (int ki = 0; ki < 4; ++ki) {
          const int kch = (ki << 1) | (quad >> 1);
          const half4 vf = *(const half4*)&VtB[row * 64 + ((kch ^ lq7) << 3) + ((quad & 1) << 2)];
          O[mi] = __builtin_amdgcn_mfma_f32_16x16x16f16(vf, pf[ki], O[mi], 0, 0, 0);
        }
      }
    }
  }

  // Epilogue (per wave; light-tile waves have complete O for their range).
  float lt = l_run;
  lt += __shfl_xor(lt, 16);
  lt += __shfl_xor(lt, 32);
  const float inv = 1.0f / lt;
  f16* yp = Y + ((size_t)(b * T_) + qrow) * C_ + h * 64;
#pragma unroll
  for (int mi = 0; mi < 4; ++mi) {
    half4 o;
    o[0] = (f16)(O[mi][0] * inv); o[1] = (f16)(O[mi][1] * inv);
    o[2] = (f16)(O[mi][2] * inv); o[3] = (f16)(O[mi][3] * inv);
    *(half4*)(yp + mi * 16 + quad * 4) = o;
  }
}

// ---------------------------------------------------------------------------
// Kernel 4: out = y @ w_proj + b_proj (fp32 out). BK=64 + swizzle.
// 128x128 tile (R8-verified; the R9 128x64 retile was neutral-to-negative).
// ---------------------------------------------------------------------------
__global__ __launch_bounds__(256) void gemm_proj(
    const f16* __restrict__ A, const f16* __restrict__ Bt,
    const float* __restrict__ bias, float* __restrict__ Out)
{
  __shared__ f16 As[128 * 64];
  __shared__ f16 Bs[128 * 64];
  const int tid  = threadIdx.x;
  const int row0 = blockIdx.y * 128;
  const int col0 = blockIdx.x * 128;
  const int wave = tid >> 6, lane = tid & 63;
  const int l = lane & 15, quad = lane >> 4;
  const int wm = wave >> 1, wn = wave & 1;
  const int sr = tid >> 3;
  const int scs = ((tid & 7) ^ (sr & 7)) * 8;
  const int lq7 = l & 7;

  f32x4 acc[4][4];
#pragma unroll
  for (int mi = 0; mi < 4; ++mi)
#pragma unroll
    for (int ni = 0; ni < 4; ++ni) acc[mi][ni] = (f32x4)0.0f;

  for (int k0 = 0; k0 < C_; k0 += 64) {
    __syncthreads();
#pragma unroll
    for (int p = 0; p < 4; ++p) {
      const int r = p * 32 + sr;
      gld16(A  + (size_t)(row0 + r) * C_ + k0 + scs, &As[p * 2048 + tid * 8]);
      gld16(Bt + (size_t)(col0 + r) * C_ + k0 + scs, &Bs[p * 2048 + tid * 8]);
    }
    __syncthreads();

#pragma unroll
    for (int s = 0; s < 2; ++s) {
      half8 af[4], bf[4];
#pragma unroll
      for (int mi = 0; mi < 4; ++mi)
        af[mi] = *(const half8*)&As[(wm * 64 + mi * 16 + l) * 64 + ((((s << 2) | quad) ^ lq7) << 3)];
#pragma unroll
      for (int ni = 0; ni < 4; ++ni)
        bf[ni] = *(const half8*)&Bs[(wn * 64 + ni * 16 + l) * 64 + ((((s << 2) | quad) ^ lq7) << 3)];
#pragma unroll
      for (int mi = 0; mi < 4; ++mi)
#pragma unroll
        for (int ni = 0; ni < 4; ++ni)
          acc[mi][ni] = __builtin_amdgcn_mfma_f32_16x16x32_f16(af[mi], bf[ni], acc[mi][ni], 0, 0, 0);
    }
  }

#pragma unroll
  for (int mi = 0; mi < 4; ++mi) {
#pragma unroll
    for (int ni = 0; ni < 4; ++ni) {
#pragma unroll
      for (int r = 0; r < 4; ++r) {
        const int gm = row0 + wm * 64 + mi * 16 + quad * 4 + r;
        const int n  = col0 + wn * 64 + ni * 16 + l;
        Out[(size_t)gm * C_ + n] = acc[mi][ni][r] + bias[n];
      }
    }
  }
}

extern "C" void kernel_launch(void* const* d_in, const int* in_sizes, int n_in,
                              void* d_out, int out_size, void* d_ws, size_t ws_size,
                              hipStream_t stream) {
  const float* x      = (const float*)d_in[0];
  const float* w_attn = (const float*)d_in[1];
  const float* b_attn = (const float*)d_in[2];
  const float* w_proj = (const float*)d_in[3];
  const float* b_proj = (const float*)d_in[4];
  float* out = (float*)d_out;

  const size_t elems = (size_t)BT_ * C_;       // 8,388,608
  f16* x16 = (f16*)d_ws;
  f16* wta = x16 + elems;
  f16* wtp = wta + (size_t)N3C * C_;
  f16* q   = wtp + (size_t)C_ * C_;
  f16* k   = q + elems;
  f16* vt  = k + elems;                        // Vt_g[bh][hd][t]
  f16* y   = vt + elems;
  float2* cs = (float2*)(y + elems);           // T_*32 float2 = 512 KB

  prep<<<dim3(5376), 256, 0, stream>>>(x, x16, w_attn, wta, w_proj, wtp, cs);
  gemm_qkv<<<dim3(N3C / 128, BT_ / 128), 256, 0, stream>>>(x16, wta, b_attn, cs, q, k, vt);
  attn_mfma<<<dim3(1024), 512, 0, stream>>>(q, k, vt, y);
  gemm_proj<<<dim3(C_ / 128, BT_ / 128), 256, 0, stream>>>(y, wtp, b_proj, out);
}

// Round 16
// 253.860 us; speedup vs baseline: 1.3040x; 1.3040x over previous
//
#include <hip/hip_runtime.h>

// Problem constants
#define B_  4
#define T_  2048
#define C_  1024
#define NH_ 16
#define HD_ 64
#define BT_ (B_*T_)   // 8192
#define N3C (3*C_)    // 3072

typedef _Float16 f16;
typedef _Float16 half8 __attribute__((ext_vector_type(8)));
typedef _Float16 half4 __attribute__((ext_vector_type(4)));
typedef _Float16 half2v __attribute__((ext_vector_type(2)));
typedef float f32x4 __attribute__((ext_vector_type(4)));

// Async global->LDS, 16 B per lane.
__device__ __forceinline__ void gld16(const f16* g, f16* l) {
  __builtin_amdgcn_global_load_lds(
      (const __attribute__((address_space(1))) unsigned int*)g,
      (__attribute__((address_space(3))) unsigned int*)l, 16, 0, 0);
}

// Single-instruction exp2 (v_exp_f32). Inputs here are bounded (scores) or
// -1e9 (mask), where HW gives 0 — no libm denormal fixup needed.
__device__ __forceinline__ float fast_exp2(float x) {
#if __has_builtin(__builtin_amdgcn_exp2f)
  return __builtin_amdgcn_exp2f(x);
#else
  return exp2f(x);
#endif
}

// Packed f32x2 -> f16x2 convert (v_cvt_pkrtz_f16_f32); bit-cast fixes the
// __fp16-vs-_Float16 ext-vector type mismatch (same bits). RTZ — used only
// for softmax p-values, NOT for input conversion.
__device__ __forceinline__ half2v cvt_pk_f16(float a, float b) {
#if __has_builtin(__builtin_amdgcn_cvt_pkrtz)
  return __builtin_bit_cast(half2v, __builtin_amdgcn_cvt_pkrtz(a, b));
#else
  half2v r; r[0] = (f16)a; r[1] = (f16)b; return r;
#endif
}

// ---------------------------------------------------------------------------
// Merged pre-pass (R8 form — the f16 x16 intermediate pays for itself via
// 24x column-block reuse in gemm_qkv; R10's fp32-A fusion doubled FETCH):
// [0,4096) cvt_x | [4096,4864) W_attn^T | [4864,5120) W_proj^T
// | [5120,5376) RoPE table.
// ---------------------------------------------------------------------------
__global__ __launch_bounds__(256) void prep(
    const float* __restrict__ X, f16* __restrict__ X16,
    const float* __restrict__ Wa, f16* __restrict__ Wta,
    const float* __restrict__ Wp, f16* __restrict__ Wtp,
    float2* __restrict__ cs)
{
  __shared__ float Ls[64][65];
  const int tid = threadIdx.x;
  const int blk = blockIdx.x;
  if (blk < 4096) {               // x fp32 -> f16
    const int i = blk * 256 + tid;
    const float4 a = ((const float4*)X)[i * 2];
    const float4 b = ((const float4*)X)[i * 2 + 1];
    half8 hx;
    hx[0] = (f16)a.x; hx[1] = (f16)a.y; hx[2] = (f16)a.z; hx[3] = (f16)a.w;
    hx[4] = (f16)b.x; hx[5] = (f16)b.y; hx[6] = (f16)b.z; hx[7] = (f16)b.w;
    ((half8*)X16)[i] = hx;
    return;
  }
  if (blk >= 5120) {              // RoPE cos/sin table
    const int i = (blk - 5120) * 256 + tid;
    const int f = i & 31, t = i >> 5;
    const float inv = expf(-(2.0f * (float)f / 64.0f) * 9.210340371976184f);
    float sn, cn;
    sincosf((float)t * inv, &sn, &cn);
    cs[i] = make_float2(cn, sn);
    return;
  }
  // Transpose + cvt: W (K x N fp32) -> Wt (N x K f16), 64x64 tiles.
  const float* W; f16* Wt; int N, i2;
  if (blk < 4864) { W = Wa; Wt = Wta; N = N3C; i2 = blk - 4096; }
  else            { W = Wp; Wt = Wtp; N = C_;  i2 = blk - 4864; }
  const int nblk = N >> 6;
  const int n0 = (i2 % nblk) * 64, k0 = (i2 / nblk) * 64;
#pragma unroll
  for (int j = 0; j < 4; ++j) {
    const int idx = j * 256 + tid;
    const int r = idx >> 4, c = (idx & 15) * 4;
    const float4 w = *(const float4*)(W + (size_t)(k0 + r) * N + n0 + c);
    Ls[r][c + 0] = w.x; Ls[r][c + 1] = w.y; Ls[r][c + 2] = w.z; Ls[r][c + 3] = w.w;
  }
  __syncthreads();
#pragma unroll
  for (int j = 0; j < 2; ++j) {
    const int idx = j * 256 + tid;
    const int r = idx >> 3, c = (idx & 7) * 8;
    half8 hw;
#pragma unroll
    for (int u = 0; u < 8; ++u) hw[u] = (f16)Ls[c + u][r];
    *(half8*)(Wt + (size_t)(n0 + r) * C_ + k0 + c) = hw;
  }
}

// ---------------------------------------------------------------------------
// Kernel 1: qkv GEMM + fused RoPE (table). BK=64, XOR-swizzled LDS,
// global_load_lds(16B) on f16 A and B (verified R8/R9, ~78 us).
// Q/K epilogue: LDS bounce -> coalesced half8 stores (verified R9).
// V epilogue: LDS transpose -> coalesced half8 stores along t (verified R5).
// ---------------------------------------------------------------------------
__global__ __launch_bounds__(256) void gemm_qkv(
    const f16* __restrict__ A, const f16* __restrict__ Bt,
    const float* __restrict__ bias, const float2* __restrict__ cs,
    f16* __restrict__ Qo, f16* __restrict__ Ko, f16* __restrict__ Vt_g)
{
  __shared__ f16 S[16384];         // As = S[0:8192), Bs = S[8192:16384)
  f16* As = S;
  f16* Bs = S + 8192;
  const int tid  = threadIdx.x;
  const int row0 = blockIdx.y * 128;
  const int col0 = blockIdx.x * 128;
  const int wave = tid >> 6, lane = tid & 63;
  const int l = lane & 15, quad = lane >> 4;
  const int wm = wave >> 1, wn = wave & 1;
  const int sr = tid >> 3;
  const int scs = ((tid & 7) ^ (sr & 7)) * 8;
  const int lq7 = l & 7;

  f32x4 acc[4][4];
#pragma unroll
  for (int mi = 0; mi < 4; ++mi)
#pragma unroll
    for (int ni = 0; ni < 4; ++ni) acc[mi][ni] = (f32x4)0.0f;

  for (int k0 = 0; k0 < C_; k0 += 64) {
    __syncthreads();
#pragma unroll
    for (int p = 0; p < 4; ++p) {
      const int r = p * 32 + sr;
      gld16(A  + (size_t)(row0 + r) * C_ + k0 + scs, &As[p * 2048 + tid * 8]);
      gld16(Bt + (size_t)(col0 + r) * C_ + k0 + scs, &Bs[p * 2048 + tid * 8]);
    }
    __syncthreads();

#pragma unroll
    for (int s = 0; s < 2; ++s) {
      half8 af[4], bf[4];
#pragma unroll
      for (int mi = 0; mi < 4; ++mi)
        af[mi] = *(const half8*)&As[(wm * 64 + mi * 16 + l) * 64 + ((((s << 2) | quad) ^ lq7) << 3)];
#pragma unroll
      for (int ni = 0; ni < 4; ++ni)
        bf[ni] = *(const half8*)&Bs[(wn * 64 + ni * 16 + l) * 64 + ((((s << 2) | quad) ^ lq7) << 3)];
#pragma unroll
      for (int mi = 0; mi < 4; ++mi)
#pragma unroll
        for (int ni = 0; ni < 4; ++ni)
          acc[mi][ni] = __builtin_amdgcn_mfma_f32_16x16x32_f16(af[mi], bf[ni], acc[mi][ni], 0, 0, 0);
    }
  }

  const int region = col0 >> 10;           // 0=q 1=k 2=v
  const int colw = col0 + wn * 64;
  const int bloc  = row0 >> 11;
  const int tbase = row0 & (T_ - 1);
  if (region < 2) {
    f16* dst = (region == 0) ? Qo : Ko;
    const float qs = (region == 0) ? 0.18033688f : 1.0f;   // 0.125*log2(e)
    // Phase 1: RoPE + bias into LDS tile S[wn][t][d], swizzled.
    __syncthreads();                        // staging-buffer reads done
#pragma unroll
    for (int mi = 0; mi < 4; ++mi) {
#pragma unroll
      for (int r = 0; r < 4; ++r) {
        const int t = wm * 64 + mi * 16 + quad * 4 + r;   // 0..127
        const int swz = ((t >> 2) & 3) << 3;
        const float2* csrow = cs + (tbase + t) * 32;
#pragma unroll
        for (int ni = 0; ni < 2; ++ni) {
          const int d = ni * 16 + l;
          const float2 c2 = csrow[d];
          const float x1 = acc[mi][ni][r]     + bias[colw + d];
          const float x2 = acc[mi][ni + 2][r] + bias[colw + d + 32];
          S[wn * 8192 + t * 64 + (d ^ swz)]        = (f16)((x1 * c2.x - x2 * c2.y) * qs);
          S[wn * 8192 + t * 64 + ((d + 32) ^ swz)] = (f16)((x2 * c2.x + x1 * c2.y) * qs);
        }
      }
    }
    __syncthreads();
    // Phase 2: coalesced half8 stores along d (8 rows x 128 B per wave instr).
#pragma unroll
    for (int j = 0; j < 8; ++j) {
      const int flat = j * 256 + tid;
      const int wnn  = flat >> 10;                      // 0..1
      const int rem  = flat & 1023;
      const int t    = rem >> 3;                        // 0..127
      const int d8   = rem & 7;                         // 0..7
      const int swz  = (t >> 2) & 3;
      const half8 v  = *(const half8*)&S[wnn * 8192 + t * 64 + ((d8 ^ swz) << 3)];
      const int hh   = ((col0 + wnn * 64) & 1023) >> 6;
      *(half8*)(dst + ((size_t)(bloc * NH_ + hh) * T_ + tbase + t) * HD_ + d8 * 8) = v;
    }
  } else {
    // V: transpose via LDS, then coalesced half8 stores along t.
    __syncthreads();                        // all staging-buffer reads done
#pragma unroll
    for (int mi = 0; mi < 4; ++mi) {
      const int t_loc = wm * 64 + mi * 16 + quad * 4;   // 4-aligned
#pragma unroll
      for (int ni = 0; ni < 4; ++ni) {
        const int d = ni * 16 + l;
        const float bs = bias[colw + d];
        half4 o;
#pragma unroll
        for (int r = 0; r < 4; ++r) o[r] = (f16)(acc[mi][ni][r] + bs);
        const int ts = t_loc ^ ((d & 15) << 3);         // swizzle keeps 4-blocks intact
        *(half4*)&S[wn * 8192 + d * 128 + ts] = o;
      }
    }
    __syncthreads();
#pragma unroll
    for (int j = 0; j < 8; ++j) {
      const int flat = j * 256 + tid;
      const int buf  = flat >> 10;                      // 0..1 (= wn half)
      const int rem  = flat & 1023;
      const int d    = rem >> 4;                        // 0..63
      const int tt   = (rem & 15) << 3;                 // 0,8,..,120
      const half8 v  = *(const half8*)&S[buf * 8192 + d * 128 + (tt ^ ((d & 15) << 3))];
      const int hh   = ((col0 + buf * 64) & 1023) >> 6;
      *(half8*)(Vt_g + ((size_t)((bloc * NH_ + hh) * HD_ + d)) * T_ + tbase + tt) = v;
    }
  }
}

// ---------------------------------------------------------------------------
// Kernel 3: MFMA flash attention — 8-WAVE SHARED-STAGING balanced pairs.
// Block = 512 threads = 8 waves, owning pair (qta=31-pr, qtb=pr).
// Waves 0-3 compute q-tile qta (16 rows each), waves 4-7 q-tile qtb, BOTH
// consuming one shared K/V staging per key-tile in a single fused k-loop.
// launch_bounds(512, 4): VGPR cap 128 — R11's (512,8) capped at 64 VGPR and
// spilled everything to scratch (VGPR=32, WRITE_SIZE 84 MB, 149 us).
// At ~104 VGPR: 4 waves/SIMD = 16 waves/CU (2 blocks x 8 waves) — same TLP
// as verified R8 (4x4), but stagings per pair 33 -> qta+1 and K/V HBM fetch
// halved. Per-wave compute code identical to verified R5/R8 body; the
// u-guard is wave-uniform, OUTSIDE the MFMA loops.
// Ping-pong safety: passing barrier kt implies all waves finished
// compute_{kt-1} (reads of buffer (kt+1)&1), so writes cannot race.
// Fixed-shift softmax, scale pre-folded into Q: p = exp2(S).
// XCD-bijective swizzle (nwg=1024): all 16 pairs of a bh on one XCD's L2.
// ---------------------------------------------------------------------------
__global__ __launch_bounds__(512, 4) void attn_mfma(
    const f16* __restrict__ Qg, const f16* __restrict__ Kg,
    const f16* __restrict__ Vt_g, f16* __restrict__ Y)
{
  __shared__ f16 Ks[2][64 * 64];   // [buf][key][hd], swizzled
  __shared__ f16 Vt[2][64 * 64];   // [buf][hd][key], swizzled
  const int tid  = threadIdx.x;
  // XCD-bijective swizzle (nwg = 1024, divisible by 8).
  const int w    = (blockIdx.x & 7) * 128 + (blockIdx.x >> 3);
  const int bh   = w >> 4;                   // 0..63
  const int pr   = w & 15;                   // pair index 0..15
  const int qta  = 31 - pr;                  // heavy q-tile (waves 0-3)
  const int qtb  = pr;                       // light q-tile (waves 4-7)
  const int b    = bh >> 4, h = bh & 15;
  const int wave = tid >> 6, lane = tid & 63;
  const int l    = lane & 15, quad = lane >> 4;
  const int lq7  = l & 7;
  const int r0   = tid >> 3, cc = tid & 7;   // r0 in [0,64): one row per thread
  const int u    = wave >> 2, wq = wave & 3; // u: which q-tile; wq: 16-row slice
  const int qt   = u ? qtb : qta;
  const int qrow = qt * 64 + wq * 16 + l;

  const f16* kbase  = Kg   + (size_t)bh * T_ * HD_;
  const f16* vtbase = Vt_g + (size_t)bh * HD_ * T_;

  // Q fragments: 16 q-rows per wave, d = 0..63 in two K=32 chunks.
  half8 qf[2];
  {
    const f16* qp = Qg + ((size_t)bh * T_ + qrow) * HD_;
    qf[0] = *(const half8*)(qp + quad * 8);
    qf[1] = *(const half8*)(qp + 32 + quad * 8);
  }

  f32x4 O[4];
#pragma unroll
  for (int mi = 0; mi < 4; ++mi) O[mi] = (f32x4)0.0f;
  float l_run = 0.f;
  const f32x4 zz = (f32x4)0.0f;              // shared MFMA C-zero

  // Prefetch tile 0 into registers (one K half8 + one V half8 per thread).
  half8 hk = *(const half8*)(kbase + (size_t)r0 * HD_ + cc * 8);
  half8 hv = *(const half8*)(vtbase + (size_t)r0 * T_ + cc * 8);

  const int nkt = qta + 1;
  const int cst = ((cc ^ (r0 & 7)) << 3);

  for (int kt = 0; kt < nkt; ++kt) {
    f16* KsB = Ks[kt & 1];
    f16* VtB = Vt[kt & 1];
    // Write prefetched tile to this iteration's LDS buffer (all 512 threads).
    *(half8*)&KsB[r0 * 64 + cst] = hk;
    *(half8*)&VtB[r0 * 64 + cst] = hv;
    __syncthreads();
    // Issue next tile's global loads; latency overlaps the compute below.
    if (kt + 1 < nkt) {
      hk = *(const half8*)(kbase + (size_t)((kt + 1) * 64 + r0) * HD_ + cc * 8);
      hv = *(const half8*)(vtbase + (size_t)r0 * T_ + (kt + 1) * 64 + cc * 8);
    }

    if (u == 0 || kt <= qtb) {               // wave-uniform
      // S^T = K · Q^T (16 q-cols per wave); first MFMA uses shared zero C.
      f32x4 St[4];
#pragma unroll
      for (int st = 0; st < 4; ++st) {
        const int row = st * 16 + l;
        const half8 af0 = *(const half8*)&KsB[row * 64 + (((quad) ^ lq7) << 3)];
        St[st] = __builtin_amdgcn_mfma_f32_16x16x32_f16(af0, qf[0], zz, 0, 0, 0);
        const half8 af1 = *(const half8*)&KsB[row * 64 + (((4 | quad) ^ lq7) << 3)];
        St[st] = __builtin_amdgcn_mfma_f32_16x16x32_f16(af1, qf[1], St[st], 0, 0, 0);
      }

      // p = exp2(S) (scale folded into Q; shift constant cancels in O/l).
      const bool domask = (kt == qt);
      const int k0 = kt * 64;
      half4 pf[4];
      float psum = 0.f;
#pragma unroll
      for (int st = 0; st < 4; ++st) {
        float pv[4];
#pragma unroll
        for (int r = 0; r < 4; ++r) {
          float x = St[st][r];
          if (domask) {
            const int key = k0 + st * 16 + quad * 4 + r;
            if (key > qrow) x = -1e9f;
          }
          const float ev = fast_exp2(x);
          pv[r] = ev;
          psum += ev;
        }
        const half2v lo = cvt_pk_f16(pv[0], pv[1]);
        const half2v hi = cvt_pk_f16(pv[2], pv[3]);
        pf[st][0] = lo[0]; pf[st][1] = lo[1];
        pf[st][2] = hi[0]; pf[st][3] = hi[1];
      }
      l_run += psum;

      // O^T += V^T · P^T.
#pragma unroll
      for (int mi = 0; mi < 4; ++mi) {
        const int row = mi * 16 + l;
#pragma unroll
        for (int ki = 0; ki < 4; ++ki) {
          const int kch = (ki << 1) | (quad >> 1);
          const half4 vf = *(const half4*)&VtB[row * 64 + ((kch ^ lq7) << 3) + ((quad & 1) << 2)];
          O[mi] = __builtin_amdgcn_mfma_f32_16x16x16f16(vf, pf[ki], O[mi], 0, 0, 0);
        }
      }
    }
  }

  // Epilogue (per wave; light-tile waves have complete O for their range).
  float lt = l_run;
  lt += __shfl_xor(lt, 16);
  lt += __shfl_xor(lt, 32);
  const float inv = 1.0f / lt;
  f16* yp = Y + ((size_t)(b * T_) + qrow) * C_ + h * 64;
#pragma unroll
  for (int mi = 0; mi < 4; ++mi) {
    half4 o;
    o[0] = (f16)(O[mi][0] * inv); o[1] = (f16)(O[mi][1] * inv);
    o[2] = (f16)(O[mi][2] * inv); o[3] = (f16)(O[mi][3] * inv);
    *(half4*)(yp + mi * 16 + quad * 4) = o;
  }
}

// ---------------------------------------------------------------------------
// Kernel 4: out = y @ w_proj + b_proj (fp32 out). BK=64 + swizzle.
// 128x128 tile (R8-verified; the R9 128x64 retile was neutral-to-negative).
// ---------------------------------------------------------------------------
__global__ __launch_bounds__(256) void gemm_proj(
    const f16* __restrict__ A, const f16* __restrict__ Bt,
    const float* __restrict__ bias, float* __restrict__ Out)
{
  __shared__ f16 As[128 * 64];
  __shared__ f16 Bs[128 * 64];
  const int tid  = threadIdx.x;
  const int row0 = blockIdx.y * 128;
  const int col0 = blockIdx.x * 128;
  const int wave = tid >> 6, lane = tid & 63;
  const int l = lane & 15, quad = lane >> 4;
  const int wm = wave >> 1, wn = wave & 1;
  const int sr = tid >> 3;
  const int scs = ((tid & 7) ^ (sr & 7)) * 8;
  const int lq7 = l & 7;

  f32x4 acc[4][4];
#pragma unroll
  for (int mi = 0; mi < 4; ++mi)
#pragma unroll
    for (int ni = 0; ni < 4; ++ni) acc[mi][ni] = (f32x4)0.0f;

  for (int k0 = 0; k0 < C_; k0 += 64) {
    __syncthreads();
#pragma unroll
    for (int p = 0; p < 4; ++p) {
      const int r = p * 32 + sr;
      gld16(A  + (size_t)(row0 + r) * C_ + k0 + scs, &As[p * 2048 + tid * 8]);
      gld16(Bt + (size_t)(col0 + r) * C_ + k0 + scs, &Bs[p * 2048 + tid * 8]);
    }
    __syncthreads();

#pragma unroll
    for (int s = 0; s < 2; ++s) {
      half8 af[4], bf[4];
#pragma unroll
      for (int mi = 0; mi < 4; ++mi)
        af[mi] = *(const half8*)&As[(wm * 64 + mi * 16 + l) * 64 + ((((s << 2) | quad) ^ lq7) << 3)];
#pragma unroll
      for (int ni = 0; ni < 4; ++ni)
        bf[ni] = *(const half8*)&Bs[(wn * 64 + ni * 16 + l) * 64 + ((((s << 2) | quad) ^ lq7) << 3)];
#pragma unroll
      for (int mi = 0; mi < 4; ++mi)
#pragma unroll
        for (int ni = 0; ni < 4; ++ni)
          acc[mi][ni] = __builtin_amdgcn_mfma_f32_16x16x32_f16(af[mi], bf[ni], acc[mi][ni], 0, 0, 0);
    }
  }

#pragma unroll
  for (int mi = 0; mi < 4; ++mi) {
#pragma unroll
    for (int ni = 0; ni < 4; ++ni) {
#pragma unroll
      for (int r = 0; r < 4; ++r) {
        const int gm = row0 + wm * 64 + mi * 16 + quad * 4 + r;
        const int n  = col0 + wn * 64 + ni * 16 + l;
        Out[(size_t)gm * C_ + n] = acc[mi][ni][r] + bias[n];
      }
    }
  }
}

extern "C" void kernel_launch(void* const* d_in, const int* in_sizes, int n_in,
                              void* d_out, int out_size, void* d_ws, size_t ws_size,
                              hipStream_t stream) {
  const float* x      = (const float*)d_in[0];
  const float* w_attn = (const float*)d_in[1];
  const float* b_attn = (const float*)d_in[2];
  const float* w_proj = (const float*)d_in[3];
  const float* b_proj = (const float*)d_in[4];
  float* out = (float*)d_out;

  const size_t elems = (size_t)BT_ * C_;       // 8,388,608
  f16* x16 = (f16*)d_ws;
  f16* wta = x16 + elems;
  f16* wtp = wta + (size_t)N3C * C_;
  f16* q   = wtp + (size_t)C_ * C_;
  f16* k   = q + elems;
  f16* vt  = k + elems;                        // Vt_g[bh][hd][t]
  f16* y   = vt + elems;
  float2* cs = (float2*)(y + elems);           // T_*32 float2 = 512 KB

  prep<<<dim3(5376), 256, 0, stream>>>(x, x16, w_attn, wta, w_proj, wtp, cs);
  gemm_qkv<<<dim3(N3C / 128, BT_ / 128), 256, 0, stream>>>(x16, wta, b_attn, cs, q, k, vt);
  attn_mfma<<<dim3(1024), 512, 0, stream>>>(q, k, vt, y);
  gemm_proj<<<dim3(C_ / 128, BT_ / 128), 256, 0, stream>>>(y, wtp, b_proj, out);
}